// Round 13
// baseline (197.037 us; speedup 1.0000x reference)
//
#include <hip/hip_runtime.h>
#include <hip/hip_bf16.h>
#include <hip/hip_fp16.h>

typedef _Float16 half8 __attribute__((ext_vector_type(8)));
typedef _Float16 half4 __attribute__((ext_vector_type(4)));
typedef float    floatx4 __attribute__((ext_vector_type(4)));

#define BM 64

// ---------------------------------------------------------------------------
// Kernel 1: W in MFMA-fragment order. Element index:
//   idx = ((((l*4 + wc)*8 + s)*4 + nf)*64 + lane), value block = 8 halves (16 B)
//   content: W^T[n][k] * scale with n = wc*64+nf*16+(lane&15),
//            k = s*32 + (lane>>4)*8 + j
// A wave's W-fragment load is contiguous: base + lane*16.
// ---------------------------------------------------------------------------
__global__ void make_weights_frag(const float* __restrict__ p0, const float* __restrict__ p1,
                                  const float* __restrict__ p2, const float* __restrict__ p3,
                                  _Float16* __restrict__ wt) {
    int idx  = blockIdx.x * blockDim.x + threadIdx.x;   // 0 .. 24575
    int lane = idx & 63;
    int nf   = (idx >> 6) & 3;
    int s    = (idx >> 8) & 7;
    int wc   = (idx >> 11) & 3;
    int l    = idx >> 13;
    int n  = wc * 64 + nf * 16 + (lane & 15);
    int k0 = s * 32 + (lane >> 4) * 8;
    const float* P[4] = {p0, p1, p2, p3};
    const float* pb = P[l + 1] + n * 20;
    float pbr[20];
    #pragma unroll
    for (int i = 0; i < 20; ++i) pbr[i] = pb[i];
    half8 o;
    #pragma unroll
    for (int j = 0; j < 8; ++j) {
        const float* pa = P[l] + (k0 + j) * 20;
        float d2 = 0.f;
        #pragma unroll
        for (int i = 0; i < 20; ++i) { float df = pa[i] - pbr[i]; d2 += df * df; }
        float d = sqrtf(d2);
        float m = fmodf(d, 0.2f);                            // == np.mod, d >= 0
        o[j] = (_Float16)(10.0f * (0.05f - fabsf(m - 0.1f)) * 0.0625f);
    }
    *reinterpret_cast<half8*>(wt + (size_t)idx * 8) = o;
}

// ---------------------------------------------------------------------------
// Kernel 2: fused 3-layer forward — R11 engine at FULL OCCUPANCY.
//   - 512 threads, 8 waves; wave wv owns all 64 rows x cols [wv*32,wv*32+32)
//     (W-dedup). Swapped MFMA operands -> vectorized half4/float4 epilogues.
//   - SINGLE 32 KB XOR-swizzled z buffer, in-place layer update, 5 barriers
//     (R4 scheme; measured equal to ping-pong's 3 barriers).
//   - __launch_bounds__(512, 8): VGPR cap 64 (demand ~52-60) -> 8 waves/SIMD
//     allowed; 32 KB LDS -> 4 blocks/CU resident = 32 waves/CU. Four
//     independent blocks destagger: one block's stage/epilogue/barrier stalls
//     are covered by the others' K-loops.
//   - W dbuf depth-1 (bb[2][2], 16 regs) + cross-layer step-0 prefetch.
//   - x staged in two 16-reg batches to bound prologue pressure.
// ---------------------------------------------------------------------------
__global__ __launch_bounds__(512, 8) void pcn_fused(
    const float* __restrict__ x, const _Float16* __restrict__ wt,
    const float* __restrict__ b1, const float* __restrict__ b2,
    const float* __restrict__ b3, float* __restrict__ out) {

    // z[row][k]: byte = row*512 + ((k/8)^(row&7))*16 + (k&7)*2
    __shared__ __align__(16) _Float16 zlds[BM * 256];   // 32,768 B

    const int t    = threadIdx.x;
    const int lane = t & 63;
    const int wv   = t >> 6;      // 0..7: column slice [wv*32, wv*32+32)
    const int l15  = lane & 15;
    const int lg   = lane >> 4;   // 0..3
    const size_t row0 = (size_t)blockIdx.x * BM;

    char* const zb = reinterpret_cast<char*>(zlds);

    half8   bb[2][2];             // W dbuf: [s&1][j], j = 16-col sub-block
    floatx4 acc[2][4];            // [j][mf]

    // W fragment address: layer l, K-step s, col sub-frag j (0..1)
    auto wfrag = [&](int l, int s, int j) -> const half8* {
        return reinterpret_cast<const half8*>(
            wt + (((size_t)l * 4 + (wv >> 1)) << 14) + s * 2048
               + ((wv & 1) * 2 + j) * 512 + lane * 8);
    };

    // ---- stage x: 64x256 f32 -> fp16 swizzled. 8 float4/thread, 2 batches.
    #pragma unroll
    for (int b = 0; b < 2; ++b) {
        floatx4 xr[4];
        #pragma unroll
        for (int i = 0; i < 4; ++i) {
            int g   = (b * 4 + i) * 512 + t;   // float4 index in [64][64]
            int row = g >> 6, c4 = g & 63;
            xr[i] = *reinterpret_cast<const floatx4*>(x + (row0 + row) * 256 + c4 * 4);
        }
        #pragma unroll
        for (int i = 0; i < 4; ++i) {
            int g   = (b * 4 + i) * 512 + t;
            int row = g >> 6, c4 = g & 63;
            half4 h;
            h[0] = (_Float16)xr[i][0]; h[1] = (_Float16)xr[i][1];
            h[2] = (_Float16)xr[i][2]; h[3] = (_Float16)xr[i][3];
            int chunk = (c4 >> 1) ^ (row & 7);
            *reinterpret_cast<half4*>(zb + row * 512 + chunk * 16 + (c4 & 1) * 8) = h;
        }
    }
    // prefetch layer-0 step-0 W while x-writes drain
    #pragma unroll
    for (int j = 0; j < 2; ++j) bb[0][j] = *wfrag(0, 0, j);
    __syncthreads();

    #pragma unroll
    for (int l = 0; l < 3; ++l) {
        const float* bias = (l == 0) ? b1 : (l == 1) ? b2 : b3;

        // bias -> accumulator init: lane holds n = wv*32 + j*16 + lg*4 + r
        #pragma unroll
        for (int j = 0; j < 2; ++j) {
            const floatx4 bv4 = *reinterpret_cast<const floatx4*>(
                bias + wv * 32 + j * 16 + lg * 4);
            #pragma unroll
            for (int mf = 0; mf < 4; ++mf)
                acc[j][mf] = bv4;
        }

        #pragma unroll
        for (int s = 0; s < 8; ++s) {            // K-step of 32
            if (s < 7) {
                #pragma unroll
                for (int j = 0; j < 2; ++j)
                    bb[(s + 1) & 1][j] = *wfrag(l, s + 1, j);
            }
            const int vchunk = (s * 4 + lg) ^ (l15 & 7);
            half8 a[4];
            #pragma unroll
            for (int mf = 0; mf < 4; ++mf)
                a[mf] = *reinterpret_cast<const half8*>(
                    zb + (mf * 16 + l15) * 512 + vchunk * 16);
            // swapped operands: D reg-axis = n (4 consecutive per lane)
            #pragma unroll
            for (int j = 0; j < 2; ++j)
                #pragma unroll
                for (int mf = 0; mf < 4; ++mf)
                    acc[j][mf] = __builtin_amdgcn_mfma_f32_16x16x32_f16(
                        bb[s & 1][j], a[mf], acc[j][mf], 0, 0, 0);
        }

        // cross-layer W prefetch: issued before the barrier, drains under epi
        if (l < 2) {
            #pragma unroll
            for (int j = 0; j < 2; ++j) bb[0][j] = *wfrag(l + 1, 0, j);
        }

        if (l < 2) {
            __syncthreads();   // all waves done READING zlds
            // relu + cvt -> zlds in place. Lane holds z[m][k0..k0+3]:
            // m = mf*16 + l15, k0 = wv*32 + j*16 + lg*4 -> one half4 per frag.
            #pragma unroll
            for (int j = 0; j < 2; ++j) {
                const int k0 = wv * 32 + j * 16 + lg * 4;
                #pragma unroll
                for (int mf = 0; mf < 4; ++mf) {
                    const int m = mf * 16 + l15;
                    half4 h;
                    #pragma unroll
                    for (int r = 0; r < 4; ++r)
                        h[r] = (_Float16)fmaxf(acc[j][mf][r], 0.0f);
                    const int byte = m * 512 + (((k0 >> 3) ^ (m & 7)) << 4)
                                   + (k0 & 7) * 2;
                    *reinterpret_cast<half4*>(zb + byte) = h;
                }
            }
            __syncthreads();   // writes visible before next layer's reads
        } else {
            // final layer: float4 stores. Lane holds out[m][n0..n0+3].
            #pragma unroll
            for (int j = 0; j < 2; ++j) {
                const int n0 = wv * 32 + j * 16 + lg * 4;
                #pragma unroll
                for (int mf = 0; mf < 4; ++mf) {
                    const size_t m = row0 + mf * 16 + l15;
                    *reinterpret_cast<floatx4*>(out + m * 256 + n0) = acc[j][mf];
                }
            }
        }
    }
}

extern "C" void kernel_launch(void* const* d_in, const int* in_sizes, int n_in,
                              void* d_out, int out_size, void* d_ws, size_t ws_size,
                              hipStream_t stream) {
    const float* x  = (const float*)d_in[0];
    const float* p0 = (const float*)d_in[1];
    const float* p1 = (const float*)d_in[2];
    const float* p2 = (const float*)d_in[3];
    const float* p3 = (const float*)d_in[4];
    const float* b1 = (const float*)d_in[5];
    const float* b2 = (const float*)d_in[6];
    const float* b3 = (const float*)d_in[7];
    float* out = (float*)d_out;
    _Float16* wt = (_Float16*)d_ws;              // 3*4*8*4*64*8 halves = 384 KB

    const int B = in_sizes[0] / 256;             // 131072

    make_weights_frag<<<96, 256, 0, stream>>>(p0, p1, p2, p3, wt);
    pcn_fused<<<B / BM, 512, 0, stream>>>(x, wt, b1, b2, b3, out);
}

// Round 14
// 103.997 us; speedup vs baseline: 1.8946x; 1.8946x over previous
//
#include <hip/hip_runtime.h>
#include <hip/hip_bf16.h>
#include <hip/hip_fp16.h>

typedef _Float16 half8 __attribute__((ext_vector_type(8)));
typedef _Float16 half4 __attribute__((ext_vector_type(4)));
typedef float    floatx4 __attribute__((ext_vector_type(4)));

#define BM 64

// ---------------------------------------------------------------------------
// Kernel 1: W in MFMA-fragment order. Element index:
//   idx = ((((l*4 + wc)*8 + s)*4 + nf)*64 + lane), value block = 8 halves (16 B)
//   content: W^T[n][k] * scale with n = wc*64+nf*16+(lane&15),
//            k = s*32 + (lane>>4)*8 + j
// A wave's W-fragment load is contiguous: base + lane*16.
// ---------------------------------------------------------------------------
__global__ void make_weights_frag(const float* __restrict__ p0, const float* __restrict__ p1,
                                  const float* __restrict__ p2, const float* __restrict__ p3,
                                  _Float16* __restrict__ wt) {
    int idx  = blockIdx.x * blockDim.x + threadIdx.x;   // 0 .. 24575
    int lane = idx & 63;
    int nf   = (idx >> 6) & 3;
    int s    = (idx >> 8) & 7;
    int wc   = (idx >> 11) & 3;
    int l    = idx >> 13;
    int n  = wc * 64 + nf * 16 + (lane & 15);
    int k0 = s * 32 + (lane >> 4) * 8;
    const float* P[4] = {p0, p1, p2, p3};
    const float* pb = P[l + 1] + n * 20;
    float pbr[20];
    #pragma unroll
    for (int i = 0; i < 20; ++i) pbr[i] = pb[i];
    half8 o;
    #pragma unroll
    for (int j = 0; j < 8; ++j) {
        const float* pa = P[l] + (k0 + j) * 20;
        float d2 = 0.f;
        #pragma unroll
        for (int i = 0; i < 20; ++i) { float df = pa[i] - pbr[i]; d2 += df * df; }
        float d = sqrtf(d2);
        float m = fmodf(d, 0.2f);                            // == np.mod, d >= 0
        o[j] = (_Float16)(10.0f * (0.05f - fabsf(m - 0.1f)) * 0.0625f);
    }
    *reinterpret_cast<half8*>(wt + (size_t)idx * 8) = o;
}

// ---------------------------------------------------------------------------
// Kernel 2: fused 3-layer forward — R11 engine, 3-blocks/CU occupancy point.
//   Unified-RF occupancy model: waves/SIMD = floor(512/(arch+AGPR)).
//   Demand here: bb 16 + a 16 + addr ~12-16 arch + acc 32 AGPR ~= 76-84 total.
//   __launch_bounds__(512,6) -> cap 85: no spill (R13's (512,8)->64 spilled),
//   and single 32 KB LDS buffer -> 3 blocks/CU = 24 waves (+50% TLP vs R9's
//   LDS-capped 16). Three independent blocks destagger stage/K/epi phases.
//   - 512 threads, 8 waves; wave wv owns all 64 rows x cols [wv*32,wv*32+32)
//     (W-dedup). Swapped MFMA operands -> vectorized half4/float4 epilogues.
//   - Single 32 KB XOR-swizzled z buffer, in-place layer update, 5 barriers.
//   - W dbuf depth-1 (bb[2][2]) + cross-layer step-0 prefetch.
// ---------------------------------------------------------------------------
__global__ __launch_bounds__(512, 6) void pcn_fused(
    const float* __restrict__ x, const _Float16* __restrict__ wt,
    const float* __restrict__ b1, const float* __restrict__ b2,
    const float* __restrict__ b3, float* __restrict__ out) {

    // z[row][k]: byte = row*512 + ((k/8)^(row&7))*16 + (k&7)*2
    __shared__ __align__(16) _Float16 zlds[BM * 256];   // 32,768 B

    const int t    = threadIdx.x;
    const int lane = t & 63;
    const int wv   = t >> 6;      // 0..7: column slice [wv*32, wv*32+32)
    const int l15  = lane & 15;
    const int lg   = lane >> 4;   // 0..3
    const size_t row0 = (size_t)blockIdx.x * BM;

    char* const zb = reinterpret_cast<char*>(zlds);

    half8   bb[2][2];             // W dbuf: [s&1][j], j = 16-col sub-block
    floatx4 acc[2][4];            // [j][mf]

    // W fragment address: layer l, K-step s, col sub-frag j (0..1)
    auto wfrag = [&](int l, int s, int j) -> const half8* {
        return reinterpret_cast<const half8*>(
            wt + (((size_t)l * 4 + (wv >> 1)) << 14) + s * 2048
               + ((wv & 1) * 2 + j) * 512 + lane * 8);
    };

    // ---- stage x: 64x256 f32 -> fp16 swizzled. 8 float4/thread, 2 batches.
    #pragma unroll
    for (int b = 0; b < 2; ++b) {
        floatx4 xr[4];
        #pragma unroll
        for (int i = 0; i < 4; ++i) {
            int g   = (b * 4 + i) * 512 + t;   // float4 index in [64][64]
            int row = g >> 6, c4 = g & 63;
            xr[i] = *reinterpret_cast<const floatx4*>(x + (row0 + row) * 256 + c4 * 4);
        }
        #pragma unroll
        for (int i = 0; i < 4; ++i) {
            int g   = (b * 4 + i) * 512 + t;
            int row = g >> 6, c4 = g & 63;
            half4 h;
            h[0] = (_Float16)xr[i][0]; h[1] = (_Float16)xr[i][1];
            h[2] = (_Float16)xr[i][2]; h[3] = (_Float16)xr[i][3];
            int chunk = (c4 >> 1) ^ (row & 7);
            *reinterpret_cast<half4*>(zb + row * 512 + chunk * 16 + (c4 & 1) * 8) = h;
        }
    }
    // prefetch layer-0 step-0 W while x-writes drain
    #pragma unroll
    for (int j = 0; j < 2; ++j) bb[0][j] = *wfrag(0, 0, j);
    __syncthreads();

    #pragma unroll
    for (int l = 0; l < 3; ++l) {
        const float* bias = (l == 0) ? b1 : (l == 1) ? b2 : b3;

        // bias -> accumulator init: lane holds n = wv*32 + j*16 + lg*4 + r
        #pragma unroll
        for (int j = 0; j < 2; ++j) {
            const floatx4 bv4 = *reinterpret_cast<const floatx4*>(
                bias + wv * 32 + j * 16 + lg * 4);
            #pragma unroll
            for (int mf = 0; mf < 4; ++mf)
                acc[j][mf] = bv4;
        }

        #pragma unroll
        for (int s = 0; s < 8; ++s) {            // K-step of 32
            if (s < 7) {
                #pragma unroll
                for (int j = 0; j < 2; ++j)
                    bb[(s + 1) & 1][j] = *wfrag(l, s + 1, j);
            }
            const int vchunk = (s * 4 + lg) ^ (l15 & 7);
            half8 a[4];
            #pragma unroll
            for (int mf = 0; mf < 4; ++mf)
                a[mf] = *reinterpret_cast<const half8*>(
                    zb + (mf * 16 + l15) * 512 + vchunk * 16);
            // swapped operands: D reg-axis = n (4 consecutive per lane)
            #pragma unroll
            for (int j = 0; j < 2; ++j)
                #pragma unroll
                for (int mf = 0; mf < 4; ++mf)
                    acc[j][mf] = __builtin_amdgcn_mfma_f32_16x16x32_f16(
                        bb[s & 1][j], a[mf], acc[j][mf], 0, 0, 0);
        }

        // cross-layer W prefetch: issued before the barrier, drains under epi
        if (l < 2) {
            #pragma unroll
            for (int j = 0; j < 2; ++j) bb[0][j] = *wfrag(l + 1, 0, j);
        }

        if (l < 2) {
            __syncthreads();   // all waves done READING zlds
            // relu + cvt -> zlds in place. Lane holds z[m][k0..k0+3]:
            // m = mf*16 + l15, k0 = wv*32 + j*16 + lg*4 -> one half4 per frag.
            #pragma unroll
            for (int j = 0; j < 2; ++j) {
                const int k0 = wv * 32 + j * 16 + lg * 4;
                #pragma unroll
                for (int mf = 0; mf < 4; ++mf) {
                    const int m = mf * 16 + l15;
                    half4 h;
                    #pragma unroll
                    for (int r = 0; r < 4; ++r)
                        h[r] = (_Float16)fmaxf(acc[j][mf][r], 0.0f);
                    const int byte = m * 512 + (((k0 >> 3) ^ (m & 7)) << 4)
                                   + (k0 & 7) * 2;
                    *reinterpret_cast<half4*>(zb + byte) = h;
                }
            }
            __syncthreads();   // writes visible before next layer's reads
        } else {
            // final layer: float4 stores. Lane holds out[m][n0..n0+3].
            #pragma unroll
            for (int j = 0; j < 2; ++j) {
                const int n0 = wv * 32 + j * 16 + lg * 4;
                #pragma unroll
                for (int mf = 0; mf < 4; ++mf) {
                    const size_t m = row0 + mf * 16 + l15;
                    *reinterpret_cast<floatx4*>(out + m * 256 + n0) = acc[j][mf];
                }
            }
        }
    }
}

extern "C" void kernel_launch(void* const* d_in, const int* in_sizes, int n_in,
                              void* d_out, int out_size, void* d_ws, size_t ws_size,
                              hipStream_t stream) {
    const float* x  = (const float*)d_in[0];
    const float* p0 = (const float*)d_in[1];
    const float* p1 = (const float*)d_in[2];
    const float* p2 = (const float*)d_in[3];
    const float* p3 = (const float*)d_in[4];
    const float* b1 = (const float*)d_in[5];
    const float* b2 = (const float*)d_in[6];
    const float* b3 = (const float*)d_in[7];
    float* out = (float*)d_out;
    _Float16* wt = (_Float16*)d_ws;              // 3*4*8*4*64*8 halves = 384 KB

    const int B = in_sizes[0] / 256;             // 131072

    make_weights_frag<<<96, 256, 0, stream>>>(p0, p1, p2, p3, wt);
    pcn_fused<<<B / BM, 512, 0, stream>>>(x, wt, b1, b2, b3, out);
}

// Round 15
// 92.676 us; speedup vs baseline: 2.1261x; 1.1222x over previous
//
#include <hip/hip_runtime.h>
#include <hip/hip_bf16.h>
#include <hip/hip_fp16.h>

typedef _Float16 half8 __attribute__((ext_vector_type(8)));
typedef _Float16 half4 __attribute__((ext_vector_type(4)));
typedef float    floatx4 __attribute__((ext_vector_type(4)));

#define BM 128

// ---------------------------------------------------------------------------
// Kernel 1: W in MFMA-fragment order. Element index:
//   idx = ((((l*4 + wc)*8 + s)*4 + nf)*64 + lane), value block = 8 halves (16 B)
//   content: W^T[n][k] * scale with n = wc*64+nf*16+(lane&15),
//            k = s*32 + (lane>>4)*8 + j
// A wave's W-fragment load is contiguous: base + lane*16.
// ---------------------------------------------------------------------------
__global__ void make_weights_frag(const float* __restrict__ p0, const float* __restrict__ p1,
                                  const float* __restrict__ p2, const float* __restrict__ p3,
                                  _Float16* __restrict__ wt) {
    int idx  = blockIdx.x * blockDim.x + threadIdx.x;   // 0 .. 24575
    int lane = idx & 63;
    int nf   = (idx >> 6) & 3;
    int s    = (idx >> 8) & 7;
    int wc   = (idx >> 11) & 3;
    int l    = idx >> 13;
    int n  = wc * 64 + nf * 16 + (lane & 15);
    int k0 = s * 32 + (lane >> 4) * 8;
    const float* P[4] = {p0, p1, p2, p3};
    const float* pb = P[l + 1] + n * 20;
    float pbr[20];
    #pragma unroll
    for (int i = 0; i < 20; ++i) pbr[i] = pb[i];
    half8 o;
    #pragma unroll
    for (int j = 0; j < 8; ++j) {
        const float* pa = P[l] + (k0 + j) * 20;
        float d2 = 0.f;
        #pragma unroll
        for (int i = 0; i < 20; ++i) { float df = pa[i] - pbr[i]; d2 += df * df; }
        float d = sqrtf(d2);
        float m = fmodf(d, 0.2f);                            // == np.mod, d >= 0
        o[j] = (_Float16)(10.0f * (0.05f - fabsf(m - 0.1f)) * 0.0625f);
    }
    *reinterpret_cast<half8*>(wt + (size_t)idx * 8) = o;
}

// ---------------------------------------------------------------------------
// Kernel 2: fused 3-layer forward — BM=128, 2x4 wave grid (amortization).
//   - Block = 128 rows x 256 cols, 512 threads, 8 waves; wave (wr,wc) owns
//     rows [wr*64, wr*64+64) x cols [wc*64, wc*64+64): acc[4][4] = 64 regs.
//     Per-block costs halve per unit work vs BM=64: W-L2/CU 2x less blocks,
//     LDS reads/CU halve (each wave reads only its 64-row half), barriers
//     and stage overhead amortize 2x, and 16 MFMAs/step give 2x per-wave ILP
//     (latency tolerance WITHOUT extra waves — R13/R14 killed the TLP lever).
//   - W direct from L2 in fragment order; wave wc reads slice wc (W-red 2:
//     row-halves share). bb[2][4] depth-1 dbuf + cross-layer prefetch.
//   - Swapped MFMA operands -> half4/float4 epilogues; bias in acc init.
//   - Single 64 KB XOR-swizzled z buffer, in-place, 5 barriers.
//   - __launch_bounds__(512,4): known-good codegen; 2 blocks/CU (128 KB LDS).
//   Register audit: acc 64 + bb 32 + a 16 + addr ~16 = ~128 (cap). Tripwire
//   on FETCH/WRITE for spills.
// ---------------------------------------------------------------------------
__global__ __launch_bounds__(512, 4) void pcn_fused(
    const float* __restrict__ x, const _Float16* __restrict__ wt,
    const float* __restrict__ b1, const float* __restrict__ b2,
    const float* __restrict__ b3, float* __restrict__ out) {

    // z[row][k]: byte = row*512 + ((k/8)^(row&7))*16 + (k&7)*2
    __shared__ __align__(16) _Float16 zlds[BM * 256];   // 65,536 B

    const int t    = threadIdx.x;
    const int lane = t & 63;
    const int wid  = t >> 6;
    const int wr   = wid >> 2;    // 0..1: row half
    const int wc   = wid & 3;     // 0..3: 64-col slice
    const int l15  = lane & 15;
    const int lg   = lane >> 4;   // 0..3
    const size_t row0 = (size_t)blockIdx.x * BM;

    char* const zb = reinterpret_cast<char*>(zlds);

    half8   bb[2][4];             // W dbuf: [s&1][j], j = 16-col block in slice
    floatx4 acc[4][4];            // [j][mf]

    // W fragment address: layer l, K-step s, col sub-frag j (0..3), slice wc
    auto wfrag = [&](int l, int s, int j) -> const half8* {
        return reinterpret_cast<const half8*>(
            wt + (((size_t)l * 4 + wc) << 14) + s * 2048 + j * 512 + lane * 8);
    };

    // ---- stage x: 128x256 f32 -> fp16 swizzled. 16 float4/thread, 4 batches.
    #pragma unroll
    for (int b = 0; b < 4; ++b) {
        floatx4 xr[4];
        #pragma unroll
        for (int i = 0; i < 4; ++i) {
            int g   = (b * 4 + i) * 512 + t;   // float4 index in [128][64]
            int row = g >> 6, c4 = g & 63;
            xr[i] = *reinterpret_cast<const floatx4*>(x + (row0 + row) * 256 + c4 * 4);
        }
        #pragma unroll
        for (int i = 0; i < 4; ++i) {
            int g   = (b * 4 + i) * 512 + t;
            int row = g >> 6, c4 = g & 63;
            half4 h;
            h[0] = (_Float16)xr[i][0]; h[1] = (_Float16)xr[i][1];
            h[2] = (_Float16)xr[i][2]; h[3] = (_Float16)xr[i][3];
            int chunk = (c4 >> 1) ^ (row & 7);
            *reinterpret_cast<half4*>(zb + row * 512 + chunk * 16 + (c4 & 1) * 8) = h;
        }
    }
    // prefetch layer-0 step-0 W while x-writes drain
    #pragma unroll
    for (int j = 0; j < 4; ++j) bb[0][j] = *wfrag(0, 0, j);
    __syncthreads();

    #pragma unroll
    for (int l = 0; l < 3; ++l) {
        const float* bias = (l == 0) ? b1 : (l == 1) ? b2 : b3;

        // bias -> accumulator init: lane holds n = wc*64 + j*16 + lg*4 + r
        #pragma unroll
        for (int j = 0; j < 4; ++j) {
            const floatx4 bv4 = *reinterpret_cast<const floatx4*>(
                bias + wc * 64 + j * 16 + lg * 4);
            #pragma unroll
            for (int mf = 0; mf < 4; ++mf)
                acc[j][mf] = bv4;
        }

        #pragma unroll
        for (int s = 0; s < 8; ++s) {            // K-step of 32
            if (s < 7) {
                #pragma unroll
                for (int j = 0; j < 4; ++j)
                    bb[(s + 1) & 1][j] = *wfrag(l, s + 1, j);
            }
            const int vchunk = (s * 4 + lg) ^ (l15 & 7);
            half8 a[4];
            #pragma unroll
            for (int mf = 0; mf < 4; ++mf)
                a[mf] = *reinterpret_cast<const half8*>(
                    zb + (wr * 64 + mf * 16 + l15) * 512 + vchunk * 16);
            // swapped operands: D reg-axis = n (4 consecutive per lane)
            #pragma unroll
            for (int j = 0; j < 4; ++j)
                #pragma unroll
                for (int mf = 0; mf < 4; ++mf)
                    acc[j][mf] = __builtin_amdgcn_mfma_f32_16x16x32_f16(
                        bb[s & 1][j], a[mf], acc[j][mf], 0, 0, 0);
        }

        // cross-layer W prefetch: issued before the barrier, drains under epi
        if (l < 2) {
            #pragma unroll
            for (int j = 0; j < 4; ++j) bb[0][j] = *wfrag(l + 1, 0, j);
        }

        if (l < 2) {
            __syncthreads();   // all waves done READING zlds
            // relu + cvt -> zlds in place. Lane holds z[m][k0..k0+3]:
            // m = wr*64 + mf*16 + l15, k0 = wc*64 + j*16 + lg*4.
            #pragma unroll
            for (int j = 0; j < 4; ++j) {
                const int k0 = wc * 64 + j * 16 + lg * 4;
                #pragma unroll
                for (int mf = 0; mf < 4; ++mf) {
                    const int m = wr * 64 + mf * 16 + l15;
                    half4 h;
                    #pragma unroll
                    for (int r = 0; r < 4; ++r)
                        h[r] = (_Float16)fmaxf(acc[j][mf][r], 0.0f);
                    const int byte = m * 512 + (((k0 >> 3) ^ (m & 7)) << 4)
                                   + (k0 & 7) * 2;
                    *reinterpret_cast<half4*>(zb + byte) = h;
                }
            }
            __syncthreads();   // writes visible before next layer's reads
        } else {
            // final layer: float4 stores. Lane holds out[m][n0..n0+3].
            #pragma unroll
            for (int j = 0; j < 4; ++j) {
                const int n0 = wc * 64 + j * 16 + lg * 4;
                #pragma unroll
                for (int mf = 0; mf < 4; ++mf) {
                    const size_t m = row0 + wr * 64 + mf * 16 + l15;
                    *reinterpret_cast<floatx4*>(out + m * 256 + n0) = acc[j][mf];
                }
            }
        }
    }
}

extern "C" void kernel_launch(void* const* d_in, const int* in_sizes, int n_in,
                              void* d_out, int out_size, void* d_ws, size_t ws_size,
                              hipStream_t stream) {
    const float* x  = (const float*)d_in[0];
    const float* p0 = (const float*)d_in[1];
    const float* p1 = (const float*)d_in[2];
    const float* p2 = (const float*)d_in[3];
    const float* p3 = (const float*)d_in[4];
    const float* b1 = (const float*)d_in[5];
    const float* b2 = (const float*)d_in[6];
    const float* b3 = (const float*)d_in[7];
    float* out = (float*)d_out;
    _Float16* wt = (_Float16*)d_ws;              // 3*4*8*4*64*8 halves = 384 KB

    const int B = in_sizes[0] / 256;             // 131072

    make_weights_frag<<<96, 256, 0, stream>>>(p0, p1, p2, p3, wt);
    pcn_fused<<<B / BM, 512, 0, stream>>>(x, wt, b1, b2, b3, out);
}